// Round 1
// baseline (427.356 us; speedup 1.0000x reference)
//
#include <hip/hip_runtime.h>

#define NN 16
#define KK 256
#define TT 1000
#define MM 384
#define TCH 16
#define NBLK_T 63   // ceil(1000/16)

__device__ __forceinline__ float fast_rcp(float x) { return __builtin_amdgcn_rcpf(x); }
__device__ __forceinline__ float silu_f(float x) {
    // x * sigmoid(x) = x / (1 + exp(-x)); safe at +-inf args
    float e = __expf(-x);
    return x * fast_rcp(1.0f + e);
}

// ---------------- K1: durations + exclusive cumsum ----------------
__global__ void k_scan(const float* __restrict__ dur_out,
                       float* __restrict__ wsS, float* __restrict__ wsD) {
    __shared__ float lds[KK];
    int n = blockIdx.x, k = threadIdx.x;
    float d = __expf(dur_out[n * KK + k]) - 1.0f;
    d = fmaxf(d, 0.0f);
    lds[k] = d;
    __syncthreads();
    float run = d;  // inclusive scan (Hillis-Steele)
    for (int off = 1; off < KK; off <<= 1) {
        float v = (k >= off) ? lds[k - off] : 0.0f;
        __syncthreads();
        run += v;
        lds[k] = run;
        __syncthreads();
    }
    wsS[n * KK + k] = run - d;  // exclusive
    wsD[n * KK + k] = d;
}

// ---------------- K2: conv1d(3,same)+BN+silu, fold into q1/qA ----------------
__global__ void k_conv(const float* __restrict__ V, const float* __restrict__ conv_w,
                       const float* __restrict__ conv_b, const float* __restrict__ bn_g,
                       const float* __restrict__ bn_b, const float* __restrict__ bn_m,
                       const float* __restrict__ bn_v, const float* __restrict__ w1,
                       const float* __restrict__ b1, const float* __restrict__ aw1,
                       const float* __restrict__ ab1, const float* __restrict__ wsD,
                       float* __restrict__ wsQ1, float* __restrict__ wsQA) {
    __shared__ __align__(16) float wt[3 * MM * 8];   // 36 KB conv weights
    __shared__ float red[32 * 8 * 8];                // partial sums
    int tid = threadIdx.x;
    int kc = blockIdx.x, n = blockIdx.y;
    for (int i = tid; i < 3 * MM * 8; i += 256) wt[i] = conv_w[i];
    __syncthreads();

    int kk = tid & 31, mg = tid >> 5;   // 32 k x 8 m-groups (48 m each)
    int k = kc * 32 + kk;
    const float* Vn = V + (size_t)n * KK * MM;
    float p[8];
#pragma unroll
    for (int c = 0; c < 8; ++c) p[c] = 0.f;
    bool ok0 = (k - 1 >= 0), ok2 = (k + 1 < KK);
    const float* v0p = Vn + (size_t)(k - 1) * MM;
    const float* v1p = Vn + (size_t)k * MM;
    const float* v2p = Vn + (size_t)(k + 1) * MM;
    int mbase = mg * 48;
    for (int mi = 0; mi < 48; ++mi) {
        int m = mbase + mi;
        float a0 = ok0 ? v0p[m] : 0.f;
        float a1 = v1p[m];
        float a2 = ok2 ? v2p[m] : 0.f;
        const float4* w0 = (const float4*)&wt[(0 * MM + m) * 8];
        const float4* w1q = (const float4*)&wt[(1 * MM + m) * 8];
        const float4* w2q = (const float4*)&wt[(2 * MM + m) * 8];
        float4 x, y;
        x = w0[0]; y = w0[1];
        p[0] = fmaf(a0, x.x, p[0]); p[1] = fmaf(a0, x.y, p[1]);
        p[2] = fmaf(a0, x.z, p[2]); p[3] = fmaf(a0, x.w, p[3]);
        p[4] = fmaf(a0, y.x, p[4]); p[5] = fmaf(a0, y.y, p[5]);
        p[6] = fmaf(a0, y.z, p[6]); p[7] = fmaf(a0, y.w, p[7]);
        x = w1q[0]; y = w1q[1];
        p[0] = fmaf(a1, x.x, p[0]); p[1] = fmaf(a1, x.y, p[1]);
        p[2] = fmaf(a1, x.z, p[2]); p[3] = fmaf(a1, x.w, p[3]);
        p[4] = fmaf(a1, y.x, p[4]); p[5] = fmaf(a1, y.y, p[5]);
        p[6] = fmaf(a1, y.z, p[6]); p[7] = fmaf(a1, y.w, p[7]);
        x = w2q[0]; y = w2q[1];
        p[0] = fmaf(a2, x.x, p[0]); p[1] = fmaf(a2, x.y, p[1]);
        p[2] = fmaf(a2, x.z, p[2]); p[3] = fmaf(a2, x.w, p[3]);
        p[4] = fmaf(a2, y.x, p[4]); p[5] = fmaf(a2, y.y, p[5]);
        p[6] = fmaf(a2, y.z, p[6]); p[7] = fmaf(a2, y.w, p[7]);
    }
#pragma unroll
    for (int c = 0; c < 8; ++c) red[(kk * 8 + mg) * 8 + c] = p[c];
    __syncthreads();

    if (tid < 32) {
        int kk2 = tid, k2 = kc * 32 + kk2;
        float cv[8];
#pragma unroll
        for (int c = 0; c < 8; ++c) {
            float s = 0.f;
#pragma unroll
            for (int mg2 = 0; mg2 < 8; ++mg2) s += red[(kk2 * 8 + mg2) * 8 + c];
            float xx = s + conv_b[c];
            float bn = (xx - bn_m[c]) * (bn_g[c] * rsqrtf(bn_v[c] + 1e-3f)) + bn_b[c];
            cv[c] = silu_f(bn);
        }
        float d = wsD[n * KK + k2];
#pragma unroll
        for (int j = 0; j < 16; ++j) {
            float q = fmaf(d, w1[16 + j], b1[j]);
#pragma unroll
            for (int c = 0; c < 8; ++c) q = fmaf(cv[c], w1[(2 + c) * 16 + j], q);
            wsQ1[((size_t)(n * KK + k2)) * 16 + j] = q;
        }
#pragma unroll
        for (int pp = 0; pp < 2; ++pp) {
            float q = fmaf(d, aw1[2 + pp], ab1[pp]);
#pragma unroll
            for (int c = 0; c < 8; ++c) q = fmaf(cv[c], aw1[(2 + c) * 2 + pp], q);
            wsQA[(size_t)(n * KK + k2) * 2 + pp] = q;
        }
    }
}

// ---------------- K3: scores -> softmax -> W@V + aux ----------------
__global__ __launch_bounds__(256) void k_main(
    const float* __restrict__ V, const float* __restrict__ w1,
    const float* __restrict__ w2g, const float* __restrict__ b2g,
    const float* __restrict__ w3g, const float* __restrict__ b3g,
    const float* __restrict__ aw1, const float* __restrict__ aw2g,
    const float* __restrict__ ab2g, const float* __restrict__ projw,
    const float* __restrict__ wsS, const float* __restrict__ wsQ1,
    const float* __restrict__ wsQA, float* __restrict__ out) {
    __shared__ __align__(16) float sc[TCH * KK];   // scores [t][k]   16 KB
    __shared__ __align__(16) float Wl[KK * 20];    // exp weights [k][t(pad20)] 20 KB
    __shared__ __align__(16) float w2l[16 * 16];
    __shared__ __align__(16) float b2l[16];
    __shared__ __align__(16) float w3l[16];
    __shared__ float wsum[TCH];
    __shared__ float wcl[TCH * 2];

    int tid = threadIdx.x;
    int tb = blockIdx.x * TCH;
    int n = blockIdx.y;
    int nK = n * KK;

    w2l[tid] = w2g[tid];
    if (tid < 16) { b2l[tid] = b2g[tid]; w3l[tid] = w3g[tid]; }

    float b3v = b3g[0];
    float rA0 = aw1[0] - aw1[2];
    float rA1 = aw1[1] - aw1[3];
    float aw200 = aw2g[0], aw201 = aw2g[1], aw210 = aw2g[2], aw211 = aw2g[3];
    float ab20 = ab2g[0], ab21 = ab2g[1];
    float r1[16];
#pragma unroll
    for (int j = 0; j < 16; ++j) r1[j] = w1[j] - w1[16 + j];

    int k = tid;
    float S_k = wsS[nK + k];
    float q1[16];
    {
        const float4* q1p = (const float4*)&wsQ1[(size_t)(nK + k) * 16];
#pragma unroll
        for (int g = 0; g < 4; ++g) {
            float4 qv = q1p[g];
            q1[4 * g + 0] = qv.x; q1[4 * g + 1] = qv.y;
            q1[4 * g + 2] = qv.z; q1[4 * g + 3] = qv.w;
        }
    }
    __syncthreads();

    // ---- phase A: scores for 16 t's (t-pairs) ----
    for (int tp = 0; tp < TCH / 2; ++tp) {
        float sA = (float)(tb + 2 * tp + 1) - S_k;
        float sB = sA + 1.0f;
        float h1a[16], h1b[16];
#pragma unroll
        for (int j = 0; j < 16; ++j) {
            h1a[j] = silu_f(fmaf(sA, r1[j], q1[j]));
            h1b[j] = silu_f(fmaf(sB, r1[j], q1[j]));
        }
        float scA = b3v, scB = b3v;
#pragma unroll
        for (int g = 0; g < 4; ++g) {
            float4 bv = *(const float4*)&b2l[g * 4];
            float aA0 = bv.x, aA1 = bv.y, aA2 = bv.z, aA3 = bv.w;
            float aB0 = bv.x, aB1 = bv.y, aB2 = bv.z, aB3 = bv.w;
#pragma unroll
            for (int j1 = 0; j1 < 16; ++j1) {
                float4 w4 = *(const float4*)&w2l[j1 * 16 + g * 4];
                float ha = h1a[j1], hb = h1b[j1];
                aA0 = fmaf(ha, w4.x, aA0); aA1 = fmaf(ha, w4.y, aA1);
                aA2 = fmaf(ha, w4.z, aA2); aA3 = fmaf(ha, w4.w, aA3);
                aB0 = fmaf(hb, w4.x, aB0); aB1 = fmaf(hb, w4.y, aB1);
                aB2 = fmaf(hb, w4.z, aB2); aB3 = fmaf(hb, w4.w, aB3);
            }
            float4 w3v = *(const float4*)&w3l[g * 4];
            scA += silu_f(aA0) * w3v.x + silu_f(aA1) * w3v.y +
                   silu_f(aA2) * w3v.z + silu_f(aA3) * w3v.w;
            scB += silu_f(aB0) * w3v.x + silu_f(aB1) * w3v.y +
                   silu_f(aB2) * w3v.z + silu_f(aB3) * w3v.w;
        }
        sc[(2 * tp) * KK + k] = scA;
        sc[(2 * tp + 1) * KK + k] = scB;
    }
    __syncthreads();

    // ---- reduce: per-wave softmax over k, aux-C accumulation ----
    {
        int wv = tid >> 6, lane = tid & 63;
        for (int i = 0; i < 4; ++i) {
            int t = wv * 4 + i;
            float v0 = sc[t * KK + lane];
            float v1 = sc[t * KK + lane + 64];
            float v2 = sc[t * KK + lane + 128];
            float v3 = sc[t * KK + lane + 192];
            float mx = fmaxf(fmaxf(v0, v1), fmaxf(v2, v3));
#pragma unroll
            for (int off = 32; off >= 1; off >>= 1) mx = fmaxf(mx, __shfl_xor(mx, off));
            float e0 = __expf(v0 - mx), e1 = __expf(v1 - mx);
            float e2 = __expf(v2 - mx), e3 = __expf(v3 - mx);
            float ssum = e0 + e1 + e2 + e3;
            float wc0 = 0.f, wc1 = 0.f;
            float tc = (float)(tb + t + 1);
            float ear[4] = {e0, e1, e2, e3};
#pragma unroll
            for (int j = 0; j < 4; ++j) {
                int kk2 = lane + 64 * j;
                float s = tc - wsS[nK + kk2];
                float qa0 = wsQA[(size_t)(nK + kk2) * 2];
                float qa1 = wsQA[(size_t)(nK + kk2) * 2 + 1];
                float a0 = silu_f(fmaf(s, rA0, qa0));
                float a1 = silu_f(fmaf(s, rA1, qa1));
                float c0 = silu_f(fmaf(a1, aw210, fmaf(a0, aw200, ab20)));
                float c1 = silu_f(fmaf(a1, aw211, fmaf(a0, aw201, ab21)));
                wc0 = fmaf(ear[j], c0, wc0);
                wc1 = fmaf(ear[j], c1, wc1);
                Wl[kk2 * 20 + t] = ear[j];
            }
#pragma unroll
            for (int off = 32; off >= 1; off >>= 1) {
                ssum += __shfl_xor(ssum, off);
                wc0 += __shfl_xor(wc0, off);
                wc1 += __shfl_xor(wc1, off);
            }
            if (lane == 0) {
                wsum[t] = ssum;
                wcl[t * 2] = wc0; wcl[t * 2 + 1] = wc1;
            }
        }
    }
    __syncthreads();

    // ---- phase B: O = (sum_k e_k * V + (sum_k e_k C_k) @ proj_w) / sum ----
    {
        int m1 = tid, m2 = tid + 256;
        bool has2 = (tid < 128);
        const float* Vn = V + (size_t)n * KK * MM;
        float acc1[16], acc2[16];
#pragma unroll
        for (int t = 0; t < 16; ++t) { acc1[t] = 0.f; acc2[t] = 0.f; }
#pragma unroll 4
        for (int kx = 0; kx < KK; ++kx) {
            const float4* Wk = (const float4*)&Wl[kx * 20];
            float wq[16];
            *(float4*)&wq[0] = Wk[0];
            *(float4*)&wq[4] = Wk[1];
            *(float4*)&wq[8] = Wk[2];
            *(float4*)&wq[12] = Wk[3];
            float vv1 = Vn[(size_t)kx * MM + m1];
#pragma unroll
            for (int t = 0; t < 16; ++t) acc1[t] = fmaf(wq[t], vv1, acc1[t]);
            if (has2) {
                float vv2 = Vn[(size_t)kx * MM + m2];
#pragma unroll
                for (int t = 0; t < 16; ++t) acc2[t] = fmaf(wq[t], vv2, acc2[t]);
            }
        }
        float pw0a = projw[m1], pw1a = projw[MM + m1];
        float pw0b = has2 ? projw[m2] : 0.f;
        float pw1b = has2 ? projw[MM + m2] : 0.f;
#pragma unroll
        for (int t = 0; t < 16; ++t) {
            int tt = tb + t;
            if (tt < TT) {
                float inv = fast_rcp(wsum[t]);
                float c0 = wcl[t * 2], c1 = wcl[t * 2 + 1];
                out[((size_t)n * TT + tt) * MM + m1] =
                    (acc1[t] + c0 * pw0a + c1 * pw1a) * inv;
                if (has2)
                    out[((size_t)n * TT + tt) * MM + m2] =
                        (acc2[t] + c0 * pw0b + c1 * pw1b) * inv;
            }
        }
    }
}

extern "C" void kernel_launch(void* const* d_in, const int* in_sizes, int n_in,
                              void* d_out, int out_size, void* d_ws, size_t ws_size,
                              hipStream_t stream) {
    const float* V   = (const float*)d_in[0];
    const float* dur = (const float*)d_in[1];
    const float* cw  = (const float*)d_in[2];
    const float* cb  = (const float*)d_in[3];
    const float* bng = (const float*)d_in[4];
    const float* bnb = (const float*)d_in[5];
    const float* bnm = (const float*)d_in[6];
    const float* bnv = (const float*)d_in[7];
    const float* w1  = (const float*)d_in[8];
    const float* b1  = (const float*)d_in[9];
    const float* w2  = (const float*)d_in[10];
    const float* b2  = (const float*)d_in[11];
    const float* w3  = (const float*)d_in[12];
    const float* b3  = (const float*)d_in[13];
    const float* aw1 = (const float*)d_in[14];
    const float* ab1 = (const float*)d_in[15];
    const float* aw2 = (const float*)d_in[16];
    const float* ab2 = (const float*)d_in[17];
    const float* pw  = (const float*)d_in[18];
    float* out = (float*)d_out;
    float* ws = (float*)d_ws;

    float* wsS  = ws;            // 4096
    float* wsD  = ws + 4096;     // 4096
    float* wsQ1 = ws + 8192;     // 65536
    float* wsQA = ws + 73728;    // 8192

    hipLaunchKernelGGL(k_scan, dim3(NN), dim3(KK), 0, stream, dur, wsS, wsD);
    hipLaunchKernelGGL(k_conv, dim3(8, NN), dim3(256), 0, stream, V, cw, cb, bng,
                       bnb, bnm, bnv, w1, b1, aw1, ab1, wsD, wsQ1, wsQA);
    hipLaunchKernelGGL(k_main, dim3(NBLK_T, NN), dim3(256), 0, stream, V, w1, w2,
                       b2, w3, b3, aw1, aw2, ab2, pw, wsS, wsQ1, wsQA, out);
}

// Round 2
// 185.014 us; speedup vs baseline: 2.3099x; 2.3099x over previous
//
#include <hip/hip_runtime.h>

#define NN 16
#define KK 256
#define TT 1000
#define MM 384
#define TCH 8      // t's per k_score block (125 blocks exactly, no tail)
#define TOB 16     // t's per k_out block
#define TP 1008    // padded T stride for E_T (4032 B, 16B-aligned rows)

__device__ __forceinline__ float fast_rcp(float x) { return __builtin_amdgcn_rcpf(x); }
__device__ __forceinline__ float silu_f(float x) {
    float e = __expf(-x);
    return x * fast_rcp(1.0f + e);
}

// ---------------- K1: durations + exclusive cumsum ----------------
__global__ void k_scan(const float* __restrict__ dur_out,
                       float* __restrict__ wsS, float* __restrict__ wsD) {
    __shared__ float lds[KK];
    int n = blockIdx.x, k = threadIdx.x;
    float d = __expf(dur_out[n * KK + k]) - 1.0f;
    d = fmaxf(d, 0.0f);
    lds[k] = d;
    __syncthreads();
    float run = d;
    for (int off = 1; off < KK; off <<= 1) {
        float v = (k >= off) ? lds[k - off] : 0.0f;
        __syncthreads();
        run += v;
        lds[k] = run;
        __syncthreads();
    }
    wsS[n * KK + k] = run - d;
    wsD[n * KK + k] = d;
}

// ---------------- K2: conv1d(3,same)+BN+silu, fold into q1/qA ----------------
__global__ void k_conv(const float* __restrict__ V, const float* __restrict__ conv_w,
                       const float* __restrict__ conv_b, const float* __restrict__ bn_g,
                       const float* __restrict__ bn_b, const float* __restrict__ bn_m,
                       const float* __restrict__ bn_v, const float* __restrict__ w1,
                       const float* __restrict__ b1, const float* __restrict__ aw1,
                       const float* __restrict__ ab1, const float* __restrict__ wsD,
                       float* __restrict__ wsQ1, float* __restrict__ wsQA) {
    __shared__ __align__(16) float wt[3 * MM * 8];
    __shared__ float red[32 * 8 * 8];
    int tid = threadIdx.x;
    int kc = blockIdx.x, n = blockIdx.y;
    for (int i = tid; i < 3 * MM * 8; i += 256) wt[i] = conv_w[i];
    __syncthreads();

    int kk = tid & 31, mg = tid >> 5;
    int k = kc * 32 + kk;
    const float* Vn = V + (size_t)n * KK * MM;
    float p[8];
#pragma unroll
    for (int c = 0; c < 8; ++c) p[c] = 0.f;
    bool ok0 = (k - 1 >= 0), ok2 = (k + 1 < KK);
    const float* v0p = Vn + (size_t)(k - 1) * MM;
    const float* v1p = Vn + (size_t)k * MM;
    const float* v2p = Vn + (size_t)(k + 1) * MM;
    int mbase = mg * 48;
    for (int mi = 0; mi < 48; ++mi) {
        int m = mbase + mi;
        float a0 = ok0 ? v0p[m] : 0.f;
        float a1 = v1p[m];
        float a2 = ok2 ? v2p[m] : 0.f;
        const float4* w0 = (const float4*)&wt[(0 * MM + m) * 8];
        const float4* w1q = (const float4*)&wt[(1 * MM + m) * 8];
        const float4* w2q = (const float4*)&wt[(2 * MM + m) * 8];
        float4 x, y;
        x = w0[0]; y = w0[1];
        p[0] = fmaf(a0, x.x, p[0]); p[1] = fmaf(a0, x.y, p[1]);
        p[2] = fmaf(a0, x.z, p[2]); p[3] = fmaf(a0, x.w, p[3]);
        p[4] = fmaf(a0, y.x, p[4]); p[5] = fmaf(a0, y.y, p[5]);
        p[6] = fmaf(a0, y.z, p[6]); p[7] = fmaf(a0, y.w, p[7]);
        x = w1q[0]; y = w1q[1];
        p[0] = fmaf(a1, x.x, p[0]); p[1] = fmaf(a1, x.y, p[1]);
        p[2] = fmaf(a1, x.z, p[2]); p[3] = fmaf(a1, x.w, p[3]);
        p[4] = fmaf(a1, y.x, p[4]); p[5] = fmaf(a1, y.y, p[5]);
        p[6] = fmaf(a1, y.z, p[6]); p[7] = fmaf(a1, y.w, p[7]);
        x = w2q[0]; y = w2q[1];
        p[0] = fmaf(a2, x.x, p[0]); p[1] = fmaf(a2, x.y, p[1]);
        p[2] = fmaf(a2, x.z, p[2]); p[3] = fmaf(a2, x.w, p[3]);
        p[4] = fmaf(a2, y.x, p[4]); p[5] = fmaf(a2, y.y, p[5]);
        p[6] = fmaf(a2, y.z, p[6]); p[7] = fmaf(a2, y.w, p[7]);
    }
#pragma unroll
    for (int c = 0; c < 8; ++c) red[(kk * 8 + mg) * 8 + c] = p[c];
    __syncthreads();

    if (tid < 32) {
        int kk2 = tid, k2 = kc * 32 + kk2;
        float cv[8];
#pragma unroll
        for (int c = 0; c < 8; ++c) {
            float s = 0.f;
#pragma unroll
            for (int mg2 = 0; mg2 < 8; ++mg2) s += red[(kk2 * 8 + mg2) * 8 + c];
            float xx = s + conv_b[c];
            float bn = (xx - bn_m[c]) * (bn_g[c] * rsqrtf(bn_v[c] + 1e-3f)) + bn_b[c];
            cv[c] = silu_f(bn);
        }
        float d = wsD[n * KK + k2];
#pragma unroll
        for (int j = 0; j < 16; ++j) {
            float q = fmaf(d, w1[16 + j], b1[j]);
#pragma unroll
            for (int c = 0; c < 8; ++c) q = fmaf(cv[c], w1[(2 + c) * 16 + j], q);
            wsQ1[((size_t)(n * KK + k2)) * 16 + j] = q;
        }
#pragma unroll
        for (int pp = 0; pp < 2; ++pp) {
            float q = fmaf(d, aw1[2 + pp], ab1[pp]);
#pragma unroll
            for (int c = 0; c < 8; ++c) q = fmaf(cv[c], aw1[(2 + c) * 2 + pp], q);
            wsQA[(size_t)(n * KK + k2) * 2 + pp] = q;
        }
    }
}

// ---------------- K3a: scores -> softmax -> normalized E_T + aux C ----------------
__global__ __launch_bounds__(256) void k_score(
    const float* __restrict__ w1, const float* __restrict__ w2g,
    const float* __restrict__ b2g, const float* __restrict__ w3g,
    const float* __restrict__ b3g, const float* __restrict__ aw1,
    const float* __restrict__ aw2g, const float* __restrict__ ab2g,
    const float* __restrict__ wsS, const float* __restrict__ wsQ1,
    const float* __restrict__ wsQA, float* __restrict__ wcg,
    float* __restrict__ ET) {
    __shared__ __align__(16) float sc[TCH * KK];   // 8 KB, scores then normalized E
    __shared__ __align__(16) float w2l[16 * 16];
    __shared__ __align__(16) float b2l[16];
    __shared__ __align__(16) float w3l[16];

    int tid = threadIdx.x;
    int tb = blockIdx.x * TCH;
    int n = blockIdx.y;
    int nK = n * KK;

    w2l[tid] = w2g[tid];
    if (tid < 16) { b2l[tid] = b2g[tid]; w3l[tid] = w3g[tid]; }

    float b3v = b3g[0];
    float rA0 = aw1[0] - aw1[2];
    float rA1 = aw1[1] - aw1[3];
    float aw200 = aw2g[0], aw201 = aw2g[1], aw210 = aw2g[2], aw211 = aw2g[3];
    float ab20 = ab2g[0], ab21 = ab2g[1];
    float r1[16];
#pragma unroll
    for (int j = 0; j < 16; ++j) r1[j] = w1[j] - w1[16 + j];

    int k = tid;
    float S_k = wsS[nK + k];
    float q1[16];
    {
        const float4* q1p = (const float4*)&wsQ1[(size_t)(nK + k) * 16];
#pragma unroll
        for (int g = 0; g < 4; ++g) {
            float4 qv = q1p[g];
            q1[4 * g + 0] = qv.x; q1[4 * g + 1] = qv.y;
            q1[4 * g + 2] = qv.z; q1[4 * g + 3] = qv.w;
        }
    }
    __syncthreads();

    // ---- phase A: scores for TCH t's (t-pairs) ----
    for (int tp = 0; tp < TCH / 2; ++tp) {
        float sA = (float)(tb + 2 * tp + 1) - S_k;
        float sB = sA + 1.0f;
        float h1a[16], h1b[16];
#pragma unroll
        for (int j = 0; j < 16; ++j) {
            h1a[j] = silu_f(fmaf(sA, r1[j], q1[j]));
            h1b[j] = silu_f(fmaf(sB, r1[j], q1[j]));
        }
        float scA = b3v, scB = b3v;
#pragma unroll
        for (int g = 0; g < 4; ++g) {
            float4 bv = *(const float4*)&b2l[g * 4];
            float aA0 = bv.x, aA1 = bv.y, aA2 = bv.z, aA3 = bv.w;
            float aB0 = bv.x, aB1 = bv.y, aB2 = bv.z, aB3 = bv.w;
#pragma unroll
            for (int j1 = 0; j1 < 16; ++j1) {
                float4 w4 = *(const float4*)&w2l[j1 * 16 + g * 4];
                float ha = h1a[j1], hb = h1b[j1];
                aA0 = fmaf(ha, w4.x, aA0); aA1 = fmaf(ha, w4.y, aA1);
                aA2 = fmaf(ha, w4.z, aA2); aA3 = fmaf(ha, w4.w, aA3);
                aB0 = fmaf(hb, w4.x, aB0); aB1 = fmaf(hb, w4.y, aB1);
                aB2 = fmaf(hb, w4.z, aB2); aB3 = fmaf(hb, w4.w, aB3);
            }
            float4 w3v = *(const float4*)&w3l[g * 4];
            scA += silu_f(aA0) * w3v.x + silu_f(aA1) * w3v.y +
                   silu_f(aA2) * w3v.z + silu_f(aA3) * w3v.w;
            scB += silu_f(aB0) * w3v.x + silu_f(aB1) * w3v.y +
                   silu_f(aB2) * w3v.z + silu_f(aB3) * w3v.w;
        }
        sc[(2 * tp) * KK + k] = scA;
        sc[(2 * tp + 1) * KK + k] = scB;
    }
    __syncthreads();

    // ---- softmax over k (wave-parallel) + aux C; normalize in place ----
    {
        int wv = tid >> 6, lane = tid & 63;
#pragma unroll
        for (int i = 0; i < 2; ++i) {
            int t = wv * 2 + i;
            int tt = tb + t;
            float v0 = sc[t * KK + lane];
            float v1 = sc[t * KK + lane + 64];
            float v2 = sc[t * KK + lane + 128];
            float v3 = sc[t * KK + lane + 192];
            float mx = fmaxf(fmaxf(v0, v1), fmaxf(v2, v3));
#pragma unroll
            for (int off = 32; off >= 1; off >>= 1) mx = fmaxf(mx, __shfl_xor(mx, off));
            float e0 = __expf(v0 - mx), e1 = __expf(v1 - mx);
            float e2 = __expf(v2 - mx), e3 = __expf(v3 - mx);
            float ssum = e0 + e1 + e2 + e3;
            float wc0 = 0.f, wc1 = 0.f;
            float tc = (float)(tt + 1);
            float ear[4] = {e0, e1, e2, e3};
#pragma unroll
            for (int j = 0; j < 4; ++j) {
                int kk2 = lane + 64 * j;
                float s = tc - wsS[nK + kk2];
                float qa0 = wsQA[(size_t)(nK + kk2) * 2];
                float qa1 = wsQA[(size_t)(nK + kk2) * 2 + 1];
                float a0 = silu_f(fmaf(s, rA0, qa0));
                float a1 = silu_f(fmaf(s, rA1, qa1));
                float c0 = silu_f(fmaf(a1, aw210, fmaf(a0, aw200, ab20)));
                float c1 = silu_f(fmaf(a1, aw211, fmaf(a0, aw201, ab21)));
                wc0 = fmaf(ear[j], c0, wc0);
                wc1 = fmaf(ear[j], c1, wc1);
            }
#pragma unroll
            for (int off = 32; off >= 1; off >>= 1) {
                ssum += __shfl_xor(ssum, off);
                wc0 += __shfl_xor(wc0, off);
                wc1 += __shfl_xor(wc1, off);
            }
            float inv = fast_rcp(ssum);
            sc[t * KK + lane]       = e0 * inv;
            sc[t * KK + lane + 64]  = e1 * inv;
            sc[t * KK + lane + 128] = e2 * inv;
            sc[t * KK + lane + 192] = e3 * inv;
            if (lane == 0) {
                wcg[(size_t)(n * TT + tt) * 2]     = wc0 * inv;
                wcg[(size_t)(n * TT + tt) * 2 + 1] = wc1 * inv;
            }
        }
    }
    __syncthreads();

    // ---- write transposed E_T[n][k][t] (normalized) ----
    for (int idx = tid; idx < TCH * KK; idx += 256) {
        int k2 = idx >> 3, t2 = idx & 7;
        ET[((size_t)(nK + k2)) * TP + tb + t2] = sc[t2 * KK + k2];
    }
}

// ---------------- K3b: O[n,t,m] = sum_k E[t,k] V[k,m] + Caux@proj ----------------
__global__ __launch_bounds__(384) void k_out(
    const float* __restrict__ V, const float* __restrict__ projw,
    const float* __restrict__ wcg, const float* __restrict__ ET,
    float* __restrict__ out) {
    int tid = threadIdx.x;
    int tb = blockIdx.x * TOB;
    int n = blockIdx.y;
    const float* Vn = V + (size_t)n * KK * MM;
    const float* Eb = ET + (size_t)n * KK * TP + tb;
    int m = tid;

    float acc[TOB];
#pragma unroll
    for (int t = 0; t < TOB; ++t) acc[t] = 0.f;

#pragma unroll 4
    for (int kx = 0; kx < KK; ++kx) {
        const float4* ep = (const float4*)(Eb + (size_t)kx * TP);
        float4 e0 = ep[0], e1 = ep[1], e2 = ep[2], e3 = ep[3];
        float vv = Vn[(size_t)kx * MM + m];
        acc[0]  = fmaf(e0.x, vv, acc[0]);  acc[1]  = fmaf(e0.y, vv, acc[1]);
        acc[2]  = fmaf(e0.z, vv, acc[2]);  acc[3]  = fmaf(e0.w, vv, acc[3]);
        acc[4]  = fmaf(e1.x, vv, acc[4]);  acc[5]  = fmaf(e1.y, vv, acc[5]);
        acc[6]  = fmaf(e1.z, vv, acc[6]);  acc[7]  = fmaf(e1.w, vv, acc[7]);
        acc[8]  = fmaf(e2.x, vv, acc[8]);  acc[9]  = fmaf(e2.y, vv, acc[9]);
        acc[10] = fmaf(e2.z, vv, acc[10]); acc[11] = fmaf(e2.w, vv, acc[11]);
        acc[12] = fmaf(e3.x, vv, acc[12]); acc[13] = fmaf(e3.y, vv, acc[13]);
        acc[14] = fmaf(e3.z, vv, acc[14]); acc[15] = fmaf(e3.w, vv, acc[15]);
    }

    float pw0 = projw[m], pw1 = projw[MM + m];
#pragma unroll
    for (int t = 0; t < TOB; ++t) {
        int tt = tb + t;
        if (tt < TT) {
            float c0 = wcg[(size_t)(n * TT + tt) * 2];
            float c1 = wcg[(size_t)(n * TT + tt) * 2 + 1];
            out[((size_t)n * TT + tt) * MM + m] = acc[t] + c0 * pw0 + c1 * pw1;
        }
    }
}

extern "C" void kernel_launch(void* const* d_in, const int* in_sizes, int n_in,
                              void* d_out, int out_size, void* d_ws, size_t ws_size,
                              hipStream_t stream) {
    const float* V   = (const float*)d_in[0];
    const float* dur = (const float*)d_in[1];
    const float* cw  = (const float*)d_in[2];
    const float* cb  = (const float*)d_in[3];
    const float* bng = (const float*)d_in[4];
    const float* bnb = (const float*)d_in[5];
    const float* bnm = (const float*)d_in[6];
    const float* bnv = (const float*)d_in[7];
    const float* w1  = (const float*)d_in[8];
    const float* b1  = (const float*)d_in[9];
    const float* w2  = (const float*)d_in[10];
    const float* b2  = (const float*)d_in[11];
    const float* w3  = (const float*)d_in[12];
    const float* b3  = (const float*)d_in[13];
    const float* aw1 = (const float*)d_in[14];
    const float* ab1 = (const float*)d_in[15];
    const float* aw2 = (const float*)d_in[16];
    const float* ab2 = (const float*)d_in[17];
    const float* pw  = (const float*)d_in[18];
    float* out = (float*)d_out;
    float* ws = (float*)d_ws;

    float* wsS  = ws;                 // 4096
    float* wsD  = ws + 4096;          // 4096
    float* wsQ1 = ws + 8192;          // 65536
    float* wsQA = ws + 73728;         // 8192
    float* wcg  = ws + 81920;         // 32768 (N*T*2 = 32000 used)
    float* ET   = ws + 114688;        // N*K*TP = 4,128,768 floats (~16.5 MB)

    hipLaunchKernelGGL(k_scan, dim3(NN), dim3(KK), 0, stream, dur, wsS, wsD);
    hipLaunchKernelGGL(k_conv, dim3(8, NN), dim3(256), 0, stream, V, cw, cb, bng,
                       bnb, bnm, bnv, w1, b1, aw1, ab1, wsD, wsQ1, wsQA);
    hipLaunchKernelGGL(k_score, dim3(TT / TCH, NN), dim3(256), 0, stream, w1, w2,
                       b2, w3, b3, aw1, aw2, ab2, wsS, wsQ1, wsQA, wcg, ET);
    hipLaunchKernelGGL(k_out, dim3((TT + TOB - 1) / TOB, NN), dim3(384), 0, stream,
                       V, pw, wcg, ET, out);
}